// Round 5
// baseline (116.884 us; speedup 1.0000x reference)
//
#include <hip/hip_runtime.h>

// NegativeSelection: score[i] = max(min_j ||x_i - s_j|| - 0.1, 0)
// N=16384, M=8192, D=128, fp32 in/out.
//
// R5: BARRIER-FREE GEMM. B fragments are streamed straight from global
// (tiled fp16 image, L2-resident 2 MB) into registers — no LDS, no
// __syncthreads in the K-loop, so no vmcnt(0) barrier drains. A fragments
// in registers for the whole block. LB(256,2): ~235 live regs, no spills
// (R4's LB(256,3) spilled: WRITE_SIZE 14.6 MB of scratch traffic).
// prep rewritten with padded-LDS transpose: both global sides coalesced.
//
// ws: Aws fp16 [N*128] tiled [tile][k8][row][8], NEGATED   (4 MB)
//     Bws fp16 [M*128] same tiling                          (2 MB)
//     b2h f32 [M]  = 0.5*|s_j|^2                            (32 KB)
//     a2  f32 [N]  = |x_i|^2                                (64 KB)
//     Pmin f32 [8][N] slot-major partial mins               (512 KB)

using half_t = _Float16;
typedef _Float16 half8 __attribute__((ext_vector_type(8)));
typedef float floatx16 __attribute__((ext_vector_type(16)));

#define TILE_ELEMS (128 * 128)

// Block = 64-row half-tile. Blocks [0, N/64): x -> Aws (negated) + a2.
// Blocks [N/64, ...): self -> Bws + b2h.
// Phase A: fully-coalesced float4 reads -> padded LDS (stride 129: the
// phase-B read pattern r*129 + k8*8 maps lane r to bank r%32, conflict-free).
// Phase B: LDS-transposed reads -> fp16 convert -> coalesced 16-B stores.
__global__ __launch_bounds__(256) void prep_kernel(
    const float* __restrict__ x, const float* __restrict__ self,
    half_t* __restrict__ Aws, half_t* __restrict__ Bws,
    float* __restrict__ b2h, float* __restrict__ a2, int nHalfA)
{
    __shared__ float sm[64 * 129];
    __shared__ float part[256];
    int bid = blockIdx.x, tid = threadIdx.x;
    bool isB = bid >= nHalfA;
    int lb = isB ? (bid - nHalfA) : bid;       // local half-tile index
    const float* src = (isB ? self : x) + (size_t)lb * (64 * 128);
    int tile = lb >> 1, h = lb & 1;
    half_t* dstT = (isB ? Bws : Aws) + (size_t)tile * TILE_ELEMS;
    float sgn = isB ? 1.f : -1.f;

    // Phase A: linear coalesced read of the 64x128 fp32 chunk.
    #pragma unroll
    for (int i = 0; i < 8; ++i) {
        int f   = i * 256 + tid;               // float4 index 0..2047
        int row = f >> 5, c4 = f & 31;
        float4 v = ((const float4*)src)[f];
        *(float4*)&sm[row * 129 + c4 * 4] = v;
    }
    __syncthreads();

    // Phase B: thread handles chunks (k8 = i*4 + tid>>6, r = tid&63).
    int r = tid & 63;
    float ss = 0.f;
    #pragma unroll
    for (int i = 0; i < 4; ++i) {
        int k8 = i * 4 + (tid >> 6);
        float4 a = *(const float4*)&sm[r * 129 + k8 * 8];
        float4 b = *(const float4*)&sm[r * 129 + k8 * 8 + 4];
        half8 hv;
        hv[0] = (half_t)(sgn * a.x); hv[1] = (half_t)(sgn * a.y);
        hv[2] = (half_t)(sgn * a.z); hv[3] = (half_t)(sgn * a.w);
        hv[4] = (half_t)(sgn * b.x); hv[5] = (half_t)(sgn * b.y);
        hv[6] = (half_t)(sgn * b.z); hv[7] = (half_t)(sgn * b.w);
        *(half8*)(dstT + (size_t)(k8 * 128 + h * 64 + r) * 8) = hv;
        ss += a.x*a.x + a.y*a.y + a.z*a.z + a.w*a.w;
        ss += b.x*b.x + b.y*b.y + b.z*b.z + b.w*b.w;
    }
    part[tid] = ss;
    __syncthreads();
    if (tid < 64) {
        float s4 = part[tid] + part[tid + 64] + part[tid + 128] + part[tid + 192];
        int grow = lb * 64 + tid;
        if (isB) b2h[grow] = 0.5f * s4;
        else     a2[grow]  = s4;
    }
}

// Grid (N/128 row-blocks, 4 M-slices) = 512 = exactly 2 blocks/CU.
// Block 256 = 4 waves 2x2; wave = 64 rows x 64 cols per 128-col tile,
// 16 tiles per slice. ZERO barriers: A frags in regs, B frags streamed
// from global (coalesced: lanes ln31 x 16 B = two contiguous 512-B runs).
__global__ __launch_bounds__(256, 2) void min_gemm_kernel(
    const half_t* __restrict__ Aws, const half_t* __restrict__ Bws,
    const float* __restrict__ b2h, float* __restrict__ Pmin, int N)
{
    int tid  = threadIdx.x;
    int lane = tid & 63;
    int wid  = tid >> 6;
    int wr   = wid >> 1, wc = wid & 1;
    int ln31 = lane & 31, lh = lane >> 5;
    int rb = blockIdx.x, s = blockIdx.y;

    // A fragments: rows wr*64 + rt*32 + ln31, k8 = ki*2 + lh.
    const half_t* Atile = Aws + (size_t)rb * TILE_ELEMS;
    half8 areg[2][8];
    #pragma unroll
    for (int rt = 0; rt < 2; ++rt)
        #pragma unroll
        for (int ki = 0; ki < 8; ++ki) {
            int k8  = ki * 2 + lh;
            int row = wr * 64 + rt * 32 + ln31;
            areg[rt][ki] = *(const half8*)(Atile + (size_t)(k8 * 128 + row) * 8);
        }

    float minacc[2][16];
    #pragma unroll
    for (int rt = 0; rt < 2; ++rt)
        #pragma unroll
        for (int r = 0; r < 16; ++r) minacc[rt][r] = 1e30f;

    int t0 = s * 16;
    for (int it = t0; it < t0 + 16; ++it) {
        const half_t* Bt = Bws + (size_t)it * TILE_ELEMS;

        // Stream this tile's B fragments into registers (no LDS).
        half8 bf0[8], bf1[8];
        #pragma unroll
        for (int ki = 0; ki < 8; ++ki) {
            int k8 = ki * 2 + lh;
            bf0[ki] = *(const half8*)(Bt + (size_t)(k8 * 128 + wc * 64 + ln31) * 8);
            bf1[ki] = *(const half8*)(Bt + (size_t)(k8 * 128 + wc * 64 + 32 + ln31) * 8);
        }

        int gcol = it * 128 + wc * 64 + ln31;
        float b2v0 = b2h[gcol];
        float b2v1 = b2h[gcol + 32];

        floatx16 acc00, acc01, acc10, acc11;
        #pragma unroll
        for (int r = 0; r < 16; ++r) {
            acc00[r] = b2v0; acc01[r] = b2v1;
            acc10[r] = b2v0; acc11[r] = b2v1;
        }

        #pragma unroll
        for (int ki = 0; ki < 8; ++ki) {
            acc00 = __builtin_amdgcn_mfma_f32_32x32x16_f16(areg[0][ki], bf0[ki], acc00, 0, 0, 0);
            acc01 = __builtin_amdgcn_mfma_f32_32x32x16_f16(areg[0][ki], bf1[ki], acc01, 0, 0, 0);
            acc10 = __builtin_amdgcn_mfma_f32_32x32x16_f16(areg[1][ki], bf0[ki], acc10, 0, 0, 0);
            acc11 = __builtin_amdgcn_mfma_f32_32x32x16_f16(areg[1][ki], bf1[ki], acc11, 0, 0, 0);
        }

        #pragma unroll
        for (int r = 0; r < 16; ++r) {
            minacc[0][r] = fminf(minacc[0][r], fminf(acc00[r], acc01[r]));
            minacc[1][r] = fminf(minacc[1][r], fminf(acc10[r], acc11[r]));
        }
    }

    // Min across 32 col-lanes; C/D row = (r&3) + 8*(r>>2) + 4*lh.
    // Slot-major Pmin: slot = s*2 + wc (the two col-waves cover different cols).
    #pragma unroll
    for (int rt = 0; rt < 2; ++rt)
        #pragma unroll
        for (int r = 0; r < 16; ++r) {
            float v = minacc[rt][r];
            #pragma unroll
            for (int m = 1; m < 32; m <<= 1)
                v = fminf(v, __shfl_xor(v, m, 64));
            if (ln31 == 0) {
                int row = rb * 128 + wr * 64 + rt * 32
                        + (r & 3) + 8 * (r >> 2) + 4 * lh;
                Pmin[(size_t)(s * 2 + wc) * N + row] = v;
            }
        }
}

// Thread per row: min of 8 slot-major partials, d2 = a2 + 2*pmin, finish.
__global__ __launch_bounds__(256) void final_kernel(
    const float* __restrict__ a2, const float* __restrict__ Pmin,
    float* __restrict__ out, int N)
{
    int i = blockIdx.x * 256 + threadIdx.x;
    float m = 1e30f;
    #pragma unroll
    for (int sl = 0; sl < 8; ++sl)
        m = fminf(m, Pmin[(size_t)sl * N + i]);
    float d2 = a2[i] + 2.f * m;
    out[i] = fmaxf(sqrtf(fmaxf(d2, 0.f)) - 0.1f, 0.f);
}

extern "C" void kernel_launch(void* const* d_in, const int* in_sizes, int n_in,
                              void* d_out, int out_size, void* d_ws, size_t ws_size,
                              hipStream_t stream)
{
    const float* x    = (const float*)d_in[0];
    const float* self = (const float*)d_in[1];
    float* out        = (float*)d_out;

    int N = in_sizes[0] / 128;   // 16384
    int M = in_sizes[1] / 128;   // 8192

    char* w      = (char*)d_ws;
    half_t* Aws  = (half_t*)w;
    half_t* Bws  = Aws + (size_t)N * 128;
    float*  b2h  = (float*)(w + (size_t)(N + M) * 128 * 2);
    float*  a2   = b2h + M;
    float*  Pmin = a2 + N;
    // ws: 4 MB + 2 MB + 32 KB + 64 KB + 512 KB ≈ 6.6 MB

    prep_kernel<<<(N + M) / 64, 256, 0, stream>>>(x, self, Aws, Bws, b2h, a2, N / 64);

    dim3 grid(N / 128, 4);       // 512 blocks = exactly 2/CU, no barriers
    min_gemm_kernel<<<grid, 256, 0, stream>>>(Aws, Bws, b2h, Pmin, N);

    final_kernel<<<N / 256, 256, 0, stream>>>(a2, Pmin, out, N);
}